// Round 12
// baseline (2057.587 us; speedup 1.0000x reference)
//
#include <hip/hip_runtime.h>
#include <cstdint>
#include <cstddef>

#define TOPK 50
#define B_ROWS 8192
#define IN_DIM 1024
#define HID_DIM 16384
#define TKT 512   // topk threads
#define CAND_CAP 1024

typedef unsigned short u16;
typedef __attribute__((ext_vector_type(8))) short bf16x8;
typedef __attribute__((ext_vector_type(4))) float f32x4;
typedef __attribute__((ext_vector_type(16))) float f32x16;

// ---------- helpers ----------
__device__ inline u16 f2bf_rne(float f) {
  unsigned u = __float_as_uint(f);
  unsigned r = 0x7FFFu + ((u >> 16) & 1u);
  return (u16)((u + r) >> 16);
}
__device__ inline float bf2f(u16 h) { return __uint_as_float(((unsigned)h) << 16); }
__device__ inline float ninf() { return __uint_as_float(0xFF800000u); }

__device__ inline void gload16(const void* g, void* l) {
  __builtin_amdgcn_global_load_lds(
      (const __attribute__((address_space(1))) void*)g,
      (__attribute__((address_space(3))) void*)l, 16, 0, 0);
}

// ---------- fused preprocessing: W_dec transpose + 3-way splits ----------
#define NT_TILES ((HID_DIM / 32) * (IN_DIM / 32))  // 16384
#define NS_BLKS 4096
__global__ __launch_bounds__(256)
void preproc_kernel(const float* __restrict__ x, const float* __restrict__ We,
                    const float* __restrict__ Wd,
                    u16* __restrict__ xh, u16* __restrict__ xm, u16* __restrict__ xl,
                    u16* __restrict__ wh, u16* __restrict__ wm, u16* __restrict__ wl,
                    u16* __restrict__ WdT) {
  __shared__ float tile[32][33];
  const int bid = blockIdx.x;
  const int tid = threadIdx.x;
  if (bid < NT_TILES) {
    const int h0 = (bid & 511) * 32;          // HID_DIM/32 = 512
    const int o0 = (bid >> 9) * 32;           // IN_DIM/32 = 32
    const int lx = tid & 31;
    const int ly = tid >> 5;  // 0..7
#pragma unroll
    for (int r = 0; r < 32; r += 8)
      tile[ly + r][lx] = Wd[(size_t)(o0 + ly + r) * HID_DIM + h0 + lx];
    __syncthreads();
#pragma unroll
    for (int r = 0; r < 32; r += 8)
      WdT[(size_t)(h0 + ly + r) * IN_DIM + o0 + lx] = f2bf_rne(tile[lx][ly + r]);
  } else {
    const int n4x = B_ROWS * IN_DIM / 4;
    const int n4w = HID_DIM * IN_DIM / 4;
    const int total = n4x + n4w;
    int i = (bid - NT_TILES) * 256 + tid;
    const int stride = NS_BLKS * 256;
    for (; i < total; i += stride) {
      const bool isX = (i < n4x);
      const int idx = isX ? i : (i - n4x);
      const float4 f = isX ? reinterpret_cast<const float4*>(x)[idx]
                           : reinterpret_cast<const float4*>(We)[idx];
      float vs[4] = {f.x, f.y, f.z, f.w};
      u16 hh[4], mm[4], ll[4];
#pragma unroll
      for (int j = 0; j < 4; ++j) {
        float v = vs[j];
        u16 a = f2bf_rne(v); float fa = bf2f(a);
        u16 b = f2bf_rne(v - fa); float fb = bf2f(b);
        u16 c = f2bf_rne(v - fa - fb);
        hh[j] = a; mm[j] = b; ll[j] = c;
      }
      const ushort4 H = make_ushort4(hh[0], hh[1], hh[2], hh[3]);
      const ushort4 M = make_ushort4(mm[0], mm[1], mm[2], mm[3]);
      const ushort4 L = make_ushort4(ll[0], ll[1], ll[2], ll[3]);
      if (isX) {
        reinterpret_cast<ushort4*>(xh)[idx] = H;
        reinterpret_cast<ushort4*>(xm)[idx] = M;
        reinterpret_cast<ushort4*>(xl)[idx] = L;
      } else {
        reinterpret_cast<ushort4*>(wh)[idx] = H;
        reinterpret_cast<ushort4*>(wm)[idx] = M;
        reinterpret_cast<ushort4*>(wl)[idx] = L;
      }
    }
  }
}

// ---------- GEMM: z = x @ W_enc^T via 6-term bf16 split MFMA, 32x32x16 ----------
// MFMA sequence (fragment values, term order hh,hm,mh,hl,mm,lh, half-step
// order h=0,1, ascending k0) BIT-IDENTICAL to round 11, whose top-50
// selection passed. Only the LDS layout changed: k-major
// [rowgroup][kslot][row][8elem], so fragment ds_read_b128s are
// lane-contiguous (512B runs; the two lane-halves alias banks 2-way = free).
// No XOR swizzle. Staging dest stays linear tid*16B (gload_lds-legal);
// source address re-derived to match (row=tid&63, kslot=tid>>6).
__global__ __launch_bounds__(256, 2)
void gemm6_kernel(const u16* __restrict__ xh, const u16* __restrict__ xm, const u16* __restrict__ xl,
                  const u16* __restrict__ wh, const u16* __restrict__ wm, const u16* __restrict__ wl,
                  float* __restrict__ z) {
  __shared__ u16 sA[3][4096];   // [rg][kslot][row][8] = 2*4*64*8
  __shared__ u16 sB[3][4096];
  const int tid = threadIdx.x;
  const int lane = tid & 63;
  const int wave = tid >> 6;
  const int wr = (wave >> 1) * 64;
  const int wc = (wave & 1) * 64;

  const int bid = blockIdx.y * gridDim.x + blockIdx.x;      // 0..8191
  const int swz = (bid & 7) * 1024 + (bid >> 3);            // bijective
  const int mg = swz >> 10;                                 // 0..7
  const int within = swz & 1023;
  const int n_idx = within >> 3;                            // 0..127
  const int m_idx = (within & 7) + mg * 8;                  // 0..63
  const int m0 = m_idx * 128;
  const int n0 = n_idx * 128;

  // staging: thread tid stages global (row = tid&63 within 64-row group,
  // kslot = tid>>6) -> LDS element tid*8 (= kslot*512 + row*8, k-major).
  const int srow = tid & 63;
  const int skk = (tid >> 6) * 8;

  const u16* gA[3] = {xh, xm, xl};
  const u16* gB[3] = {wh, wm, wl};

  const size_t aoff = (size_t)(m0 + srow) * IN_DIM + skk;
  const size_t boff = (size_t)(n0 + srow) * IN_DIM + skk;

  f32x16 acc[2][2] = {};

  const int rsel = lane & 31;      // row/col within 32-tile
  const int usel = lane >> 5;      // k half-group

  const int argA = (wr >> 6) * 2048;   // rowgroup base for this wave's A rows
  const int argB = (wc >> 6) * 2048;

  for (int k0 = 0; k0 < IN_DIM; k0 += 32) {
#pragma unroll
    for (int s = 0; s < 3; ++s) {
      gload16(gA[s] + aoff + k0,                 &sA[s][tid * 8]);
      gload16(gA[s] + aoff + k0 + 64 * IN_DIM,   &sA[s][2048 + tid * 8]);
      gload16(gB[s] + boff + k0,                 &sB[s][tid * 8]);
      gload16(gB[s] + boff + k0 + 64 * IN_DIM,   &sB[s][2048 + tid * 8]);
    }
    __syncthreads();
    // two K16 half-steps per staged K32 tile (same order as r11)
#pragma unroll
    for (int h = 0; h < 2; ++h) {
      const int g = h * 2 + usel;  // kslot (0..3) within the staged tile
      bf16x8 a[3][2], b[3][2];
#pragma unroll
      for (int t = 0; t < 2; ++t) {
        const int ea = argA + g * 512 + (t * 32 + rsel) * 8;
        const int eb = argB + g * 512 + (t * 32 + rsel) * 8;
#pragma unroll
        for (int s = 0; s < 3; ++s) {
          a[s][t] = *reinterpret_cast<const bf16x8*>(&sA[s][ea]);
          b[s][t] = *reinterpret_cast<const bf16x8*>(&sB[s][eb]);
        }
      }
#define TERM32(SA, SB)                                                       \
      _Pragma("unroll")                                                      \
      for (int mt = 0; mt < 2; ++mt)                                         \
        _Pragma("unroll")                                                    \
        for (int nt = 0; nt < 2; ++nt)                                       \
          acc[mt][nt] = __builtin_amdgcn_mfma_f32_32x32x16_bf16(             \
              a[SA][mt], b[SB][nt], acc[mt][nt], 0, 0, 0);
      TERM32(0, 0)  // hh
      TERM32(0, 1)  // hm
      TERM32(1, 0)  // mh
      TERM32(0, 2)  // hl
      TERM32(1, 1)  // mm
      TERM32(2, 0)  // lh
#undef TERM32
    }
    __syncthreads();
  }
  // epilogue: C/D layout col=lane&31, row=(reg&3)+8*(reg>>2)+4*usel
  const int col = lane & 31;
#pragma unroll
  for (int mt = 0; mt < 2; ++mt)
#pragma unroll
    for (int nt = 0; nt < 2; ++nt)
#pragma unroll
      for (int reg = 0; reg < 16; ++reg) {
        const int rr = m0 + wr + mt * 32 + (reg & 3) + 8 * (reg >> 2) + 4 * usel;
        const int cc = n0 + wc + nt * 32 + col;
        z[(size_t)rr * HID_DIM + cc] = acc[mt][nt][reg];
      }
}

// ---------- fused exact top-50 + sparsify + decode (register-resident) ----------
// UNCHANGED from rounds 9-11.
__global__ __launch_bounds__(TKT)
void topk_decode_kernel(float* __restrict__ z, const u16* __restrict__ WdT,
                        float* __restrict__ recon) {
  __shared__ float cval[CAND_CAP];     // 4 KiB
  __shared__ int   cidx[CAND_CAP];     // 4 KiB
  __shared__ float sredv[TKT / 64];
  __shared__ int   sredi[TKT / 64];
  __shared__ unsigned scnt;
  __shared__ float sthr, ssig;
  __shared__ float sBv;
  __shared__ int   sBi;

  const int tid = threadIdx.x;
  const int lane = tid & 63;
  const int wv = tid >> 6;
  const size_t row = blockIdx.x;
  float* zrow = z + row * HID_DIM;

  float4 rr[8];
  float ss = 0.f;
#pragma unroll
  for (int j = 0; j < 8; ++j) {
    rr[j] = *reinterpret_cast<const float4*>(zrow + j * 2048 + tid * 4);
    ss = fmaf(rr[j].x, rr[j].x, ss); ss = fmaf(rr[j].y, rr[j].y, ss);
    ss = fmaf(rr[j].z, rr[j].z, ss); ss = fmaf(rr[j].w, rr[j].w, ss);
  }
#pragma unroll
  for (int off = 32; off > 0; off >>= 1) ss += __shfl_down(ss, off);
  if (lane == 0) sredv[wv] = ss;
  __syncthreads();
  if (tid == 0) {
    float t = 0.f;
#pragma unroll
    for (int w = 0; w < TKT / 64; ++w) t += sredv[w];
    float sig = sqrtf(t / (float)HID_DIM);
    ssig = sig;
    sthr = 2.6f * sig;
  }
  __syncthreads();

  int cnt = 0;
  bool ok = false;
  for (int att = 0; att < 4; ++att) {
    if (tid == 0) scnt = 0;
    __syncthreads();
    const float th = sthr;
#define COLLECT(V, IDX)                                          \
    do { const float v_ = (V);                                   \
      if (v_ > th) {                                             \
        unsigned p = atomicAdd(&scnt, 1u);                       \
        if (p < CAND_CAP) { cval[p] = v_; cidx[p] = (IDX); }     \
      } } while (0)
#pragma unroll
    for (int j = 0; j < 8; ++j) {
      const int base = j * 2048 + tid * 4;
      COLLECT(rr[j].x, base);
      COLLECT(rr[j].y, base + 1);
      COLLECT(rr[j].z, base + 2);
      COLLECT(rr[j].w, base + 3);
    }
#undef COLLECT
    __syncthreads();
    cnt = (int)scnt;
    if (cnt >= TOPK && cnt <= CAND_CAP) { ok = true; break; }
    if (tid == 0) sthr = (cnt < TOPK) ? (sthr - 0.7f * ssig) : (sthr + 0.7f * ssig);
    __syncthreads();
  }

  if (!ok) {
    unsigned msk = 0;
    for (int r = 0; r < TOPK; ++r) {
      float bv = ninf(); int bi = 0x7FFFFFFF;
#define FBCHK(V, B, BIT)                                          \
      if (!((msk >> (BIT)) & 1u)) {                               \
        const float v_ = (V);                                     \
        if (v_ > bv || (v_ == bv && (B) < bi)) { bv = v_; bi = (B); } }
#pragma unroll
      for (int j = 0; j < 8; ++j) {
        const int base = j * 2048 + tid * 4;
        FBCHK(rr[j].x, base,     j * 4 + 0)
        FBCHK(rr[j].y, base + 1, j * 4 + 1)
        FBCHK(rr[j].z, base + 2, j * 4 + 2)
        FBCHK(rr[j].w, base + 3, j * 4 + 3)
      }
#undef FBCHK
#pragma unroll
      for (int off = 32; off > 0; off >>= 1) {
        float ov = __shfl_down(bv, off); int oi = __shfl_down(bi, off);
        if (ov > bv || (ov == bv && oi < bi)) { bv = ov; bi = oi; }
      }
      if (lane == 0) { sredv[wv] = bv; sredi[wv] = bi; }
      __syncthreads();
      if (tid == 0) {
        float Bv = ninf(); int Bi = 0x7FFFFFFF;
#pragma unroll
        for (int w = 0; w < TKT / 64; ++w) {
          if (sredv[w] > Bv || (sredv[w] == Bv && sredi[w] < Bi)) { Bv = sredv[w]; Bi = sredi[w]; }
        }
        cval[r] = Bv; cidx[r] = Bi; sBv = Bv; sBi = Bi;
      }
      __syncthreads();
      const int Bi = sBi;
      const int owner = (Bi & 2047) >> 2;
      if (tid == owner) msk |= 1u << ((Bi >> 11) * 4 + (Bi & 3));
      __syncthreads();
    }
    cnt = TOPK;
  }

  int P2 = 64;
  while (P2 < cnt) P2 <<= 1;
  for (int i = cnt + tid; i < P2; i += TKT) { cval[i] = ninf(); cidx[i] = 0x7FFFFFFF; }
  __syncthreads();
  for (int k = 2; k <= P2; k <<= 1) {
    for (int j = k >> 1; j > 0; j >>= 1) {
      for (int i = tid; i < P2; i += TKT) {
        const int l = i ^ j;
        if (l > i) {
          float va = cval[i], vb = cval[l];
          int ia = cidx[i], ib = cidx[l];
          const bool aGreater = (va > vb) || (va == vb && ia < ib);
          const bool up = ((i & k) == 0);
          if (up ? !aGreater : aGreater) {
            cval[i] = vb; cval[l] = va;
            cidx[i] = ib; cidx[l] = ia;
          }
        }
      }
      __syncthreads();
    }
  }

  const float T = cval[TOPK - 1];
  const int lastTie = cidx[TOPK - 1];

#pragma unroll
  for (int j = 0; j < 8; ++j) {
    const int base = j * 2048 + tid * 4;
    float4 o;
    o.x = (rr[j].x > T || (rr[j].x == T && base     <= lastTie)) ? rr[j].x : 0.0f;
    o.y = (rr[j].y > T || (rr[j].y == T && base + 1 <= lastTie)) ? rr[j].y : 0.0f;
    o.z = (rr[j].z > T || (rr[j].z == T && base + 2 <= lastTie)) ? rr[j].z : 0.0f;
    o.w = (rr[j].w > T || (rr[j].w == T && base + 3 <= lastTie)) ? rr[j].w : 0.0f;
    *reinterpret_cast<float4*>(zrow + base) = o;
  }

  float a0 = 0.f, a1 = 0.f;
  for (int j = 0; j < TOPK; ++j) {
    const float v = cval[j];
    const unsigned w2 = reinterpret_cast<const unsigned*>(WdT + (size_t)cidx[j] * IN_DIM)[tid];
    a0 = fmaf(v, __uint_as_float(w2 << 16), a0);
    a1 = fmaf(v, __uint_as_float(w2 & 0xFFFF0000u), a1);
  }
  reinterpret_cast<float2*>(recon + row * IN_DIM)[tid] = make_float2(a0, a1);
}

// ---------- launch ----------
extern "C" void kernel_launch(void* const* d_in, const int* in_sizes, int n_in,
                              void* d_out, int out_size, void* d_ws, size_t ws_size,
                              hipStream_t stream) {
  const float* x  = (const float*)d_in[0];
  const float* We = (const float*)d_in[1];
  const float* Wd = (const float*)d_in[2];
  float* recon = (float*)d_out;
  float* z = recon + (size_t)B_ROWS * IN_DIM;   // outputs concatenated: recon, z

  char* ws = (char*)d_ws;
  const size_t MB = 1024ull * 1024ull;
  u16* xh = (u16*)(ws + 0 * MB);     // 16 MiB each (8192x1024 bf16)
  u16* xm = (u16*)(ws + 16 * MB);
  u16* xl = (u16*)(ws + 32 * MB);
  u16* wh = (u16*)(ws + 48 * MB);    // 32 MiB each (16384x1024 bf16)
  u16* wmm = (u16*)(ws + 80 * MB);
  u16* wl = (u16*)(ws + 112 * MB);
  u16* WdT = (u16*)(ws + 144 * MB);  // 32 MiB (bf16)

  preproc_kernel<<<NT_TILES + NS_BLKS, 256, 0, stream>>>(
      x, We, Wd, xh, xm, xl, wh, wmm, wl, WdT);
  gemm6_kernel<<<dim3(HID_DIM / 128, B_ROWS / 128), 256, 0, stream>>>(xh, xm, xl, wh, wmm, wl, z);
  topk_decode_kernel<<<B_ROWS, TKT, 0, stream>>>(z, WdT, recon);
}

// Round 13
// 1502.327 us; speedup vs baseline: 1.3696x; 1.3696x over previous
//
#include <hip/hip_runtime.h>
#include <cstdint>
#include <cstddef>

#define TOPK 50
#define B_ROWS 8192
#define IN_DIM 1024
#define HID_DIM 16384
#define TKT 512   // topk threads
#define CAND_CAP 1024

typedef unsigned short u16;
typedef __attribute__((ext_vector_type(8))) short bf16x8;
typedef __attribute__((ext_vector_type(4))) float f32x4;

// ---------- helpers ----------
__device__ inline u16 f2bf_rne(float f) {
  unsigned u = __float_as_uint(f);
  unsigned r = 0x7FFFu + ((u >> 16) & 1u);
  return (u16)((u + r) >> 16);
}
__device__ inline float bf2f(u16 h) { return __uint_as_float(((unsigned)h) << 16); }
__device__ inline float ninf() { return __uint_as_float(0xFF800000u); }

__device__ inline void gload16(const void* g, void* l) {
  __builtin_amdgcn_global_load_lds(
      (const __attribute__((address_space(1))) void*)g,
      (__attribute__((address_space(3))) void*)l, 16, 0, 0);
}

// ---------- fused preprocessing: W_dec transpose + 3-way splits ----------
#define NT_TILES ((HID_DIM / 32) * (IN_DIM / 32))  // 16384
#define NS_BLKS 4096
__global__ __launch_bounds__(256)
void preproc_kernel(const float* __restrict__ x, const float* __restrict__ We,
                    const float* __restrict__ Wd,
                    u16* __restrict__ xh, u16* __restrict__ xm, u16* __restrict__ xl,
                    u16* __restrict__ wh, u16* __restrict__ wm, u16* __restrict__ wl,
                    u16* __restrict__ WdT) {
  __shared__ float tile[32][33];
  const int bid = blockIdx.x;
  const int tid = threadIdx.x;
  if (bid < NT_TILES) {
    const int h0 = (bid & 511) * 32;          // HID_DIM/32 = 512
    const int o0 = (bid >> 9) * 32;           // IN_DIM/32 = 32
    const int lx = tid & 31;
    const int ly = tid >> 5;  // 0..7
#pragma unroll
    for (int r = 0; r < 32; r += 8)
      tile[ly + r][lx] = Wd[(size_t)(o0 + ly + r) * HID_DIM + h0 + lx];
    __syncthreads();
#pragma unroll
    for (int r = 0; r < 32; r += 8)
      WdT[(size_t)(h0 + ly + r) * IN_DIM + o0 + lx] = f2bf_rne(tile[lx][ly + r]);
  } else {
    const int n4x = B_ROWS * IN_DIM / 4;
    const int n4w = HID_DIM * IN_DIM / 4;
    const int total = n4x + n4w;
    int i = (bid - NT_TILES) * 256 + tid;
    const int stride = NS_BLKS * 256;
    for (; i < total; i += stride) {
      const bool isX = (i < n4x);
      const int idx = isX ? i : (i - n4x);
      const float4 f = isX ? reinterpret_cast<const float4*>(x)[idx]
                           : reinterpret_cast<const float4*>(We)[idx];
      float vs[4] = {f.x, f.y, f.z, f.w};
      u16 hh[4], mm[4], ll[4];
#pragma unroll
      for (int j = 0; j < 4; ++j) {
        float v = vs[j];
        u16 a = f2bf_rne(v); float fa = bf2f(a);
        u16 b = f2bf_rne(v - fa); float fb = bf2f(b);
        u16 c = f2bf_rne(v - fa - fb);
        hh[j] = a; mm[j] = b; ll[j] = c;
      }
      const ushort4 H = make_ushort4(hh[0], hh[1], hh[2], hh[3]);
      const ushort4 M = make_ushort4(mm[0], mm[1], mm[2], mm[3]);
      const ushort4 L = make_ushort4(ll[0], ll[1], ll[2], ll[3]);
      if (isX) {
        reinterpret_cast<ushort4*>(xh)[idx] = H;
        reinterpret_cast<ushort4*>(xm)[idx] = M;
        reinterpret_cast<ushort4*>(xl)[idx] = L;
      } else {
        reinterpret_cast<ushort4*>(wh)[idx] = H;
        reinterpret_cast<ushort4*>(wm)[idx] = M;
        reinterpret_cast<ushort4*>(wl)[idx] = L;
      }
    }
  }
}

// ---------- GEMM: z = x @ W_enc^T via 6-term bf16 split MFMA ----------
// Round-10 kernel VERBATIM (best measured: ~1220us, MfmaUtil ~73% +
// VALUBusy ~24% = issue-saturated, 0 bank conflicts; its accumulation
// chain's top-50 selection is proven across rounds 1-10).
__global__ __launch_bounds__(256, 2)
void gemm6_kernel(const u16* __restrict__ xh, const u16* __restrict__ xm, const u16* __restrict__ xl,
                  const u16* __restrict__ wh, const u16* __restrict__ wm, const u16* __restrict__ wl,
                  float* __restrict__ z) {
  __shared__ u16 sA[3][128 * 32];
  __shared__ u16 sB[3][128 * 32];
  const int tid = threadIdx.x;
  const int lane = tid & 63;
  const int wave = tid >> 6;
  const int wr = (wave >> 1) * 64;
  const int wc = (wave & 1) * 64;

  const int bid = blockIdx.y * gridDim.x + blockIdx.x;      // 0..8191
  const int swz = (bid & 7) * 1024 + (bid >> 3);            // bijective
  const int mg = swz >> 10;                                 // 0..7
  const int within = swz & 1023;
  const int n_idx = within >> 3;                            // 0..127
  const int m_idx = (within & 7) + mg * 8;                  // 0..63
  const int m0 = m_idx * 128;
  const int n0 = n_idx * 128;

  const int srow = tid >> 2;
  const int scol = (((tid & 3) ^ ((srow >> 1) & 3)) * 8);

  const u16* gA[3] = {xh, xm, xl};
  const u16* gB[3] = {wh, wm, wl};

  const size_t aoff = (size_t)(m0 + srow) * IN_DIM + scol;
  const size_t boff = (size_t)(n0 + srow) * IN_DIM + scol;

  f32x4 acc[4][4] = {};

  const int rsel = lane & 15;
  const int ksel = (lane >> 4) * 8;

  for (int k0 = 0; k0 < IN_DIM; k0 += 32) {
#pragma unroll
    for (int s = 0; s < 3; ++s) {
      gload16(gA[s] + aoff + k0,                 &sA[s][tid * 8]);
      gload16(gA[s] + aoff + k0 + 64 * IN_DIM,   &sA[s][2048 + tid * 8]);
      gload16(gB[s] + boff + k0,                 &sB[s][tid * 8]);
      gload16(gB[s] + boff + k0 + 64 * IN_DIM,   &sB[s][2048 + tid * 8]);
    }
    __syncthreads();
    bf16x8 a[3][4], b[3][4];
#pragma unroll
    for (int t = 0; t < 4; ++t) {
      const int ra = wr + t * 16 + rsel;
      const int rb = wc + t * 16 + rsel;
      const int ka = ksel ^ (((ra >> 1) & 3) * 8);
      const int kb = ksel ^ (((rb >> 1) & 3) * 8);
#pragma unroll
      for (int s = 0; s < 3; ++s) {
        a[s][t] = *reinterpret_cast<const bf16x8*>(&sA[s][ra * 32 + ka]);
        b[s][t] = *reinterpret_cast<const bf16x8*>(&sB[s][rb * 32 + kb]);
      }
    }
#define TERM(SA, SB)                                                         \
    _Pragma("unroll")                                                        \
    for (int mt = 0; mt < 4; ++mt)                                           \
      _Pragma("unroll")                                                      \
      for (int nt = 0; nt < 4; ++nt)                                         \
        acc[mt][nt] = __builtin_amdgcn_mfma_f32_16x16x32_bf16(               \
            a[SA][mt], b[SB][nt], acc[mt][nt], 0, 0, 0);
    TERM(0, 0)  // hh
    TERM(0, 1)  // hm
    TERM(1, 0)  // mh
    TERM(0, 2)  // hl
    TERM(1, 1)  // mm
    TERM(2, 0)  // lh
#undef TERM
    __syncthreads();
  }
  const int col = lane & 15;
  const int r0 = (lane >> 4) * 4;
#pragma unroll
  for (int mt = 0; mt < 4; ++mt)
#pragma unroll
    for (int nt = 0; nt < 4; ++nt)
#pragma unroll
      for (int j = 0; j < 4; ++j) {
        const int rr = m0 + wr + mt * 16 + r0 + j;
        const int cc = n0 + wc + nt * 16 + col;
        z[(size_t)rr * HID_DIM + cc] = acc[mt][nt][j];
      }
}

// ---------- fused exact top-50 + sparsify + decode (register-resident) ----------
__global__ __launch_bounds__(TKT)
void topk_decode_kernel(float* __restrict__ z, const u16* __restrict__ WdT,
                        float* __restrict__ recon) {
  __shared__ float cval[CAND_CAP];     // 4 KiB
  __shared__ int   cidx[CAND_CAP];     // 4 KiB
  __shared__ float sredv[TKT / 64];
  __shared__ int   sredi[TKT / 64];
  __shared__ unsigned scnt;
  __shared__ float sthr, ssig;
  __shared__ float sBv;
  __shared__ int   sBi;

  const int tid = threadIdx.x;
  const int lane = tid & 63;
  const int wv = tid >> 6;
  const size_t row = blockIdx.x;
  float* zrow = z + row * HID_DIM;

  float4 rr[8];
  float ss = 0.f;
#pragma unroll
  for (int j = 0; j < 8; ++j) {
    rr[j] = *reinterpret_cast<const float4*>(zrow + j * 2048 + tid * 4);
    ss = fmaf(rr[j].x, rr[j].x, ss); ss = fmaf(rr[j].y, rr[j].y, ss);
    ss = fmaf(rr[j].z, rr[j].z, ss); ss = fmaf(rr[j].w, rr[j].w, ss);
  }
#pragma unroll
  for (int off = 32; off > 0; off >>= 1) ss += __shfl_down(ss, off);
  if (lane == 0) sredv[wv] = ss;
  __syncthreads();
  if (tid == 0) {
    float t = 0.f;
#pragma unroll
    for (int w = 0; w < TKT / 64; ++w) t += sredv[w];
    float sig = sqrtf(t / (float)HID_DIM);
    ssig = sig;
    sthr = 2.6f * sig;
  }
  __syncthreads();

  int cnt = 0;
  bool ok = false;
  for (int att = 0; att < 4; ++att) {
    if (tid == 0) scnt = 0;
    __syncthreads();
    const float th = sthr;
#define COLLECT(V, IDX)                                          \
    do { const float v_ = (V);                                   \
      if (v_ > th) {                                             \
        unsigned p = atomicAdd(&scnt, 1u);                       \
        if (p < CAND_CAP) { cval[p] = v_; cidx[p] = (IDX); }     \
      } } while (0)
#pragma unroll
    for (int j = 0; j < 8; ++j) {
      const int base = j * 2048 + tid * 4;
      COLLECT(rr[j].x, base);
      COLLECT(rr[j].y, base + 1);
      COLLECT(rr[j].z, base + 2);
      COLLECT(rr[j].w, base + 3);
    }
#undef COLLECT
    __syncthreads();
    cnt = (int)scnt;
    if (cnt >= TOPK && cnt <= CAND_CAP) { ok = true; break; }
    if (tid == 0) sthr = (cnt < TOPK) ? (sthr - 0.7f * ssig) : (sthr + 0.7f * ssig);
    __syncthreads();
  }

  if (!ok) {
    unsigned msk = 0;
    for (int r = 0; r < TOPK; ++r) {
      float bv = ninf(); int bi = 0x7FFFFFFF;
#define FBCHK(V, B, BIT)                                          \
      if (!((msk >> (BIT)) & 1u)) {                               \
        const float v_ = (V);                                     \
        if (v_ > bv || (v_ == bv && (B) < bi)) { bv = v_; bi = (B); } }
#pragma unroll
      for (int j = 0; j < 8; ++j) {
        const int base = j * 2048 + tid * 4;
        FBCHK(rr[j].x, base,     j * 4 + 0)
        FBCHK(rr[j].y, base + 1, j * 4 + 1)
        FBCHK(rr[j].z, base + 2, j * 4 + 2)
        FBCHK(rr[j].w, base + 3, j * 4 + 3)
      }
#undef FBCHK
#pragma unroll
      for (int off = 32; off > 0; off >>= 1) {
        float ov = __shfl_down(bv, off); int oi = __shfl_down(bi, off);
        if (ov > bv || (ov == bv && oi < bi)) { bv = ov; bi = oi; }
      }
      if (lane == 0) { sredv[wv] = bv; sredi[wv] = bi; }
      __syncthreads();
      if (tid == 0) {
        float Bv = ninf(); int Bi = 0x7FFFFFFF;
#pragma unroll
        for (int w = 0; w < TKT / 64; ++w) {
          if (sredv[w] > Bv || (sredv[w] == Bv && sredi[w] < Bi)) { Bv = sredv[w]; Bi = sredi[w]; }
        }
        cval[r] = Bv; cidx[r] = Bi; sBv = Bv; sBi = Bi;
      }
      __syncthreads();
      const int Bi = sBi;
      const int owner = (Bi & 2047) >> 2;
      if (tid == owner) msk |= 1u << ((Bi >> 11) * 4 + (Bi & 3));
      __syncthreads();
    }
    cnt = TOPK;
  }

  int P2 = 64;
  while (P2 < cnt) P2 <<= 1;
  for (int i = cnt + tid; i < P2; i += TKT) { cval[i] = ninf(); cidx[i] = 0x7FFFFFFF; }
  __syncthreads();
  for (int k = 2; k <= P2; k <<= 1) {
    for (int j = k >> 1; j > 0; j >>= 1) {
      for (int i = tid; i < P2; i += TKT) {
        const int l = i ^ j;
        if (l > i) {
          float va = cval[i], vb = cval[l];
          int ia = cidx[i], ib = cidx[l];
          const bool aGreater = (va > vb) || (va == vb && ia < ib);
          const bool up = ((i & k) == 0);
          if (up ? !aGreater : aGreater) {
            cval[i] = vb; cval[l] = va;
            cidx[i] = ib; cidx[l] = ia;
          }
        }
      }
      __syncthreads();
    }
  }

  const float T = cval[TOPK - 1];
  const int lastTie = cidx[TOPK - 1];

#pragma unroll
  for (int j = 0; j < 8; ++j) {
    const int base = j * 2048 + tid * 4;
    float4 o;
    o.x = (rr[j].x > T || (rr[j].x == T && base     <= lastTie)) ? rr[j].x : 0.0f;
    o.y = (rr[j].y > T || (rr[j].y == T && base + 1 <= lastTie)) ? rr[j].y : 0.0f;
    o.z = (rr[j].z > T || (rr[j].z == T && base + 2 <= lastTie)) ? rr[j].z : 0.0f;
    o.w = (rr[j].w > T || (rr[j].w == T && base + 3 <= lastTie)) ? rr[j].w : 0.0f;
    *reinterpret_cast<float4*>(zrow + base) = o;
  }

  float a0 = 0.f, a1 = 0.f;
  for (int j = 0; j < TOPK; ++j) {
    const float v = cval[j];
    const unsigned w2 = reinterpret_cast<const unsigned*>(WdT + (size_t)cidx[j] * IN_DIM)[tid];
    a0 = fmaf(v, __uint_as_float(w2 << 16), a0);
    a1 = fmaf(v, __uint_as_float(w2 & 0xFFFF0000u), a1);
  }
  reinterpret_cast<float2*>(recon + row * IN_DIM)[tid] = make_float2(a0, a1);
}

// ---------- launch ----------
extern "C" void kernel_launch(void* const* d_in, const int* in_sizes, int n_in,
                              void* d_out, int out_size, void* d_ws, size_t ws_size,
                              hipStream_t stream) {
  const float* x  = (const float*)d_in[0];
  const float* We = (const float*)d_in[1];
  const float* Wd = (const float*)d_in[2];
  float* recon = (float*)d_out;
  float* z = recon + (size_t)B_ROWS * IN_DIM;   // outputs concatenated: recon, z

  char* ws = (char*)d_ws;
  const size_t MB = 1024ull * 1024ull;
  u16* xh = (u16*)(ws + 0 * MB);     // 16 MiB each (8192x1024 bf16)
  u16* xm = (u16*)(ws + 16 * MB);
  u16* xl = (u16*)(ws + 32 * MB);
  u16* wh = (u16*)(ws + 48 * MB);    // 32 MiB each (16384x1024 bf16)
  u16* wmm = (u16*)(ws + 80 * MB);
  u16* wl = (u16*)(ws + 112 * MB);
  u16* WdT = (u16*)(ws + 144 * MB);  // 32 MiB (bf16)

  preproc_kernel<<<NT_TILES + NS_BLKS, 256, 0, stream>>>(
      x, We, Wd, xh, xm, xl, wh, wmm, wl, WdT);
  gemm6_kernel<<<dim3(HID_DIM / 128, B_ROWS / 128), 256, 0, stream>>>(xh, xm, xl, wh, wmm, wl, z);
  topk_decode_kernel<<<B_ROWS, TKT, 0, stream>>>(z, WdT, recon);
}